// Round 1
// baseline (51.368 us; speedup 1.0000x reference)
//
#include <hip/hip_runtime.h>

// out[b, n, s, e] = in[b, s + n - LEFT, e]  (0 if src row out of range)
// B=8, S=2048, E=512, N=5, LEFT=2. All fp32.
// Vectorized as float4: E4 = 128 float4 per row.

#define NG_B 8
#define NG_S 2048
#define NG_E 512
#define NG_N 5
#define NG_LEFT 2
#define NG_E4 (NG_E / 4)          // 128
#define NG_TOTAL4 (NG_B * NG_N * NG_S * NG_E4)  // 10,485,760

__global__ __launch_bounds__(256) void ngram_kernel(const float4* __restrict__ in,
                                                    float4* __restrict__ out) {
    const unsigned stride = gridDim.x * blockDim.x;
    for (unsigned i = blockIdx.x * blockDim.x + threadIdx.x; i < NG_TOTAL4; i += stride) {
        const unsigned e4 = i & (NG_E4 - 1);          // i % 128
        const unsigned t  = i >> 7;                    // / 128
        const unsigned s  = t & (NG_S - 1);            // t % 2048
        const unsigned t2 = t >> 11;                   // b*5 + n, < 40
        const unsigned n  = t2 % NG_N;
        const unsigned b  = t2 / NG_N;
        const int src_s = (int)s + (int)n - NG_LEFT;
        float4 v = make_float4(0.f, 0.f, 0.f, 0.f);
        if (src_s >= 0 && src_s < NG_S) {
            v = in[(((unsigned)(b * NG_S + src_s)) << 7) + e4];
        }
        out[i] = v;
    }
}

extern "C" void kernel_launch(void* const* d_in, const int* in_sizes, int n_in,
                              void* d_out, int out_size, void* d_ws, size_t ws_size,
                              hipStream_t stream) {
    const float4* in = (const float4*)d_in[0];
    float4* out = (float4*)d_out;
    const int block = 256;
    const int grid = 2048;   // 8 blocks/CU on 256 CUs; grid-stride covers the rest
    ngram_kernel<<<grid, block, 0, stream>>>(in, out);
}

// Round 2
// 34.603 us; speedup vs baseline: 1.4845x; 1.4845x over previous
//
#include <hip/hip_runtime.h>

// out[b, n, s, e] = in[b, s + n - 2, e]  (0 if src row out of range)
// B=8, S=2048, E=512, N=5. fp32, vectorized as float4 (E4 = 128 per row).
//
// SCATTER formulation: thread i loads input float4 i once, stores it to the
// 5 output rows it contributes to:  out[b, n, s_src + 2 - n, e].
// Boundary-zero rows (6 per batch) are written by 24 extra fused blocks.

#define NG_S 2048
#define NG_E4 128
#define NBLK_MAIN 8192   // 8*2048*128 / 256
#define NBLK_ZERO 24     // 8 batches * 6 rows * 128 float4 / 256

__global__ __launch_bounds__(256) void ngram_scatter(const float4* __restrict__ in,
                                                     float4* __restrict__ out) {
    const unsigned bid = blockIdx.x;
    if (bid < NBLK_MAIN) {
        const unsigned i  = bid * 256u + threadIdx.x;   // input float4 index
        const unsigned e4 = i & (NG_E4 - 1);
        const unsigned t  = i >> 7;                      // b*2048 + s_src
        const unsigned s  = t & (NG_S - 1);
        const unsigned b  = t >> 11;
        const float4 v = in[i];
        const unsigned bn = b * 5u;
        #pragma unroll
        for (int n = 0; n < 5; ++n) {
            const int s_out = (int)s + 2 - n;            // wave-uniform branch
            if (s_out >= 0 && s_out < (int)NG_S) {
                out[((((bn + (unsigned)n) << 11) + (unsigned)s_out) << 7) + e4] = v;
            }
        }
    } else {
        // zero-fill the 6 out-of-range rows per batch
        const unsigned j  = (bid - NBLK_MAIN) * 256u + threadIdx.x;  // < 6144
        const unsigned e4 = j & (NG_E4 - 1);
        const unsigned r  = j >> 7;                      // < 48
        const unsigned b  = r / 6u;
        const unsigned k  = r - b * 6u;
        unsigned n, sx;
        switch (k) {
            case 0: n = 0; sx = 0;    break;
            case 1: n = 0; sx = 1;    break;
            case 2: n = 1; sx = 0;    break;
            case 3: n = 3; sx = 2047; break;
            case 4: n = 4; sx = 2046; break;
            default: n = 4; sx = 2047; break;
        }
        out[(((b * 5u + n) << 11) + sx << 7) + e4] = make_float4(0.f, 0.f, 0.f, 0.f);
    }
}

extern "C" void kernel_launch(void* const* d_in, const int* in_sizes, int n_in,
                              void* d_out, int out_size, void* d_ws, size_t ws_size,
                              hipStream_t stream) {
    const float4* in = (const float4*)d_in[0];
    float4* out = (float4*)d_out;
    ngram_scatter<<<NBLK_MAIN + NBLK_ZERO, 256, 0, stream>>>(in, out);
}